// Round 7
// baseline (463.173 us; speedup 1.0000x reference)
//
#include <hip/hip_runtime.h>
#include <math.h>

#define WL     256
#define HOP    128
#define NW     239      // (30720 - 256)/128 + 1
#define NBINS  129
#define NSAMP  30720
#define NROWS  (64*23)  // 1472

// One 64-lane wave per frame. 128-pt complex FFT fully in registers:
// each lane holds 2 points (slot = bit6). Stage h=64 is lane-local; stages
// h=32..1 exchange via shfl_xor (no LDS -> no bank conflicts). One tiny
// LDS scatter puts Z in natural order for the conflict-free rfft untangle.
__global__ __launch_bounds__(64) void stft_kernel(const float* __restrict__ sig,
                                                  float* __restrict__ out) {
    const int l   = threadIdx.x;           // 0..63
    const int bid = blockIdx.x;            // row*NW + w
    const int row = bid / NW;
    const int w   = bid - row * NW;
    const float* __restrict__ src = sig + (size_t)row * NSAMP + (size_t)w * HOP;

    __shared__ __align__(8) float zre[128];
    __shared__ __align__(8) float zim[128];

    // ---- load 4 samples as 2x float2 (8B coalesced), apply Hann
    // element l     = x[2l]   + i*x[2l+1]
    // element l+64  = x[2l+128] + i*x[2l+129]
    float2 xa = *reinterpret_cast<const float2*>(src + 2 * l);
    float2 xb = *reinterpret_cast<const float2*>(src + 2 * l + 128);
    // np.hanning(256): w(n) = 0.5 - 0.5*cos(2*pi*n/255) = 0.5 - 0.5*cospi(2n/255)
    float w0 = 0.5f - 0.5f * cospif((float)(4 * l)       * (1.0f / 255.0f));
    float w1 = 0.5f - 0.5f * cospif((float)(4 * l + 2)   * (1.0f / 255.0f));
    float w2 = 0.5f - 0.5f * cospif((float)(4 * l + 256) * (1.0f / 255.0f));
    float w3 = 0.5f - 0.5f * cospif((float)(4 * l + 258) * (1.0f / 255.0f));
    float v0r = xa.x * w0, v0i = xa.y * w1;   // slot 0: index l
    float v1r = xb.x * w2, v1i = xb.y * w3;   // slot 1: index l+64

    // ---- stage h=64 (lane-local): pairs (l, l+64), W_128^l = exp(-i*pi*l/64)
    {
        float s, c;
        sincospif((float)l * (1.0f / 64.0f), &s, &c);
        float tr = v0r - v1r, ti = v0i - v1i;
        v0r += v1r; v0i += v1i;
        v1r = tr * c + ti * s;                // (tr+i*ti)*(c - i*s)
        v1i = ti * c - tr * s;
    }

    // ---- stages h = 32,16,8,4 (cross-lane, branchless select)
    #pragma unroll
    for (int m = 32; m >= 4; m >>= 1) {
        float s, c;
        sincospif((float)(l & (m - 1)) * (1.0f / (float)m), &s, &c);
        const bool up = (l & m) != 0;
        float p0r = __shfl_xor(v0r, m), p0i = __shfl_xor(v0i, m);
        float p1r = __shfl_xor(v1r, m), p1i = __shfl_xor(v1i, m);
        float dr = p0r - v0r, di = p0i - v0i;
        float wr = dr * c + di * s, wi = di * c - dr * s;
        v0r = up ? wr : (v0r + p0r);
        v0i = up ? wi : (v0i + p0i);
        dr = p1r - v1r; di = p1i - v1i;
        wr = dr * c + di * s; wi = di * c - dr * s;
        v1r = up ? wr : (v1r + p1r);
        v1i = up ? wi : (v1i + p1i);
    }

    // ---- stage h=2: twiddle is 1 (j=0) or -i (j=1); role = bit1, j = bit0
    {
        const bool up = (l & 2) != 0;
        const bool j1 = (l & 1) != 0;
        float p0r = __shfl_xor(v0r, 2), p0i = __shfl_xor(v0i, 2);
        float p1r = __shfl_xor(v1r, 2), p1i = __shfl_xor(v1i, 2);
        float dr = p0r - v0r, di = p0i - v0i;
        float wr = j1 ? di : dr, wi = j1 ? -dr : di;   // d * (-i) when j=1
        v0r = up ? wr : (v0r + p0r);
        v0i = up ? wi : (v0i + p0i);
        dr = p1r - v1r; di = p1i - v1i;
        wr = j1 ? di : dr; wi = j1 ? -dr : di;
        v1r = up ? wr : (v1r + p1r);
        v1i = up ? wi : (v1i + p1i);
    }

    // ---- stage h=1: twiddle 1; role = bit0
    {
        const bool up = (l & 1) != 0;
        float p0r = __shfl_xor(v0r, 1), p0i = __shfl_xor(v0i, 1);
        float p1r = __shfl_xor(v1r, 1), p1i = __shfl_xor(v1i, 1);
        v0r = up ? (p0r - v0r) : (v0r + p0r);
        v0i = up ? (p0i - v0i) : (v0i + p0i);
        v1r = up ? (p1r - v1r) : (v1r + p1r);
        v1i = up ? (p1i - v1i) : (v1i + p1i);
    }

    // ---- DIF output: storage (l, slot r) holds Z[2*brev6(l) + r].
    // Scatter to natural order via float2 (slots are adjacent).
    const int pn = (int)(__brev((unsigned)l) >> 26);   // brev6(l)
    reinterpret_cast<float2*>(zre)[pn] = make_float2(v0r, v1r);
    reinterpret_cast<float2*>(zim)[pn] = make_float2(v0i, v1i);
    __syncthreads();

    // ---- rfft untangle (natural-order, stride-1 conflict-free reads)
    float* __restrict__ o = out + (size_t)bid * NBINS;
    #pragma unroll
    for (int q = 0; q < 2; ++q) {
        int k  = l + 64 * q;                // 0..127
        int km = (128 - k) & 127;
        float zkr = zre[k],  zki = zim[k];
        float zmr = zre[km], zmi = zim[km];
        float er  = 0.5f * (zkr + zmr);
        float ei  = 0.5f * (zki - zmi);
        float orr = 0.5f * (zki + zmi);
        float oi  = -0.5f * (zkr - zmr);
        float s, c;
        sincospif((float)k * (1.0f / 128.0f), &s, &c);   // W_256^k = c - i*s
        float Xr = er + c * orr + s * oi;
        float Xi = ei + c * oi - s * orr;
        float mag = sqrtf(Xr * Xr + Xi * Xi);
        // log(x)*10 == log2(x)*10*ln2 ; v_log_f32 is native log2
        o[k] = __log2f(mag + 1e-8f) * 6.931471805599453f;
    }
    if (l == 0) {
        float Xr = zre[0] - zim[0];          // k=128: Re(Z0) - Im(Z0)
        o[128] = __log2f(fabsf(Xr) + 1e-8f) * 6.931471805599453f;
    }
}

extern "C" void kernel_launch(void* const* d_in, const int* in_sizes, int n_in,
                              void* d_out, int out_size, void* d_ws, size_t ws_size,
                              hipStream_t stream) {
    const float* sig = (const float*)d_in[0];
    float* out = (float*)d_out;
    (void)in_sizes; (void)n_in; (void)out_size; (void)d_ws; (void)ws_size;
    const int nblocks = NROWS * NW;        // 351,808 frames
    stft_kernel<<<dim3(nblocks), dim3(64), 0, stream>>>(sig, out);
}

// Round 8
// 373.001 us; speedup vs baseline: 1.2417x; 1.2417x over previous
//
#include <hip/hip_runtime.h>
#include <math.h>

#define WL     256
#define HOP    128
#define NW     239      // (30720 - 256)/128 + 1
#define NBINS  129
#define NSAMP  30720
#define NROWS  (64*23)  // 1472
#define NFRAMES (NROWS * NW)   // 351,808
#define NBLOCKS 8192
#define FPB     43             // ceil(NFRAMES / NBLOCKS)

// One 64-lane wave per block; each block processes FPB consecutive frames.
// All twiddles/window coeffs (frame-invariant) hoisted out of the frame loop.
// 128-pt register FFT via shfl_xor; tiny LDS scatter for natural-order untangle.
__global__ __launch_bounds__(64) void stft_kernel(const float* __restrict__ sig,
                                                  float* __restrict__ out) {
    const int l = threadIdx.x;             // 0..63

    __shared__ __align__(8) float zre[128];
    __shared__ __align__(8) float zim[128];

    // ======== frame-invariant per-lane constants (computed ONCE) ========
    // Hann: np.hanning(256) w(n) = 0.5 - 0.5*cospi(2n/255)
    const float w0 = 0.5f - 0.5f * cospif((float)(4 * l)       * (1.0f / 255.0f));
    const float w1 = 0.5f - 0.5f * cospif((float)(4 * l + 2)   * (1.0f / 255.0f));
    const float w2 = 0.5f - 0.5f * cospif((float)(4 * l + 256) * (1.0f / 255.0f));
    const float w3 = 0.5f - 0.5f * cospif((float)(4 * l + 258) * (1.0f / 255.0f));
    float c64, s64;  sincospif((float)l * (1.0f / 64.0f), &s64, &c64);
    float c32, s32;  sincospif((float)(l & 31) * (1.0f / 32.0f), &s32, &c32);
    float c16, s16;  sincospif((float)(l & 15) * (1.0f / 16.0f), &s16, &c16);
    float c8,  s8;   sincospif((float)(l & 7)  * (1.0f / 8.0f),  &s8,  &c8);
    float c4,  s4;   sincospif((float)(l & 3)  * (1.0f / 4.0f),  &s4,  &c4);
    float cu0, su0;  sincospif((float)l        * (1.0f / 128.0f), &su0, &cu0);        // k = l
    float cu1, su1;  sincospif((float)(l + 64) * (1.0f / 128.0f), &su1, &cu1);        // k = l+64
    const int pn  = (int)(__brev((unsigned)l) >> 26);  // brev6(l), scatter target
    const int km0 = (128 - l) & 127;                   // mirror index for k=l
    const int km1 = 64 - l;                            // mirror for k=l+64 (128-(l+64))&127, l<64

    const int f0   = blockIdx.x * FPB;
    const int fend = (f0 + FPB < NFRAMES) ? f0 + FPB : NFRAMES;

    for (int f = f0; f < fend; ++f) {
        const int row = f / NW;            // wave-uniform -> scalar magic-mul
        const int w   = f - row * NW;
        const float* __restrict__ src = sig + (size_t)row * NSAMP + (size_t)w * HOP;

        // ---- load 4 samples (2x float2, coalesced), window, pack complex
        float2 xa = *reinterpret_cast<const float2*>(src + 2 * l);
        float2 xb = *reinterpret_cast<const float2*>(src + 2 * l + 128);
        float v0r = xa.x * w0, v0i = xa.y * w1;   // element l
        float v1r = xb.x * w2, v1i = xb.y * w3;   // element l+64

        // ---- stage h=64 (lane-local), W_128^l
        {
            float tr = v0r - v1r, ti = v0i - v1i;
            v0r += v1r; v0i += v1i;
            v1r = tr * c64 + ti * s64;            // (tr+i*ti)*(c - i*s)
            v1i = ti * c64 - tr * s64;
        }

        // ---- stages h = 32,16,8,4 (cross-lane, hoisted twiddles)
        #define XSTAGE(m, cc, ss)                                         \
        {                                                                 \
            const bool up = (l & (m)) != 0;                               \
            float p0r = __shfl_xor(v0r, (m)), p0i = __shfl_xor(v0i, (m)); \
            float p1r = __shfl_xor(v1r, (m)), p1i = __shfl_xor(v1i, (m)); \
            float dr = p0r - v0r, di = p0i - v0i;                         \
            float wr = dr * (cc) + di * (ss), wi = di * (cc) - dr * (ss); \
            v0r = up ? wr : (v0r + p0r);                                  \
            v0i = up ? wi : (v0i + p0i);                                  \
            dr = p1r - v1r; di = p1i - v1i;                               \
            wr = dr * (cc) + di * (ss); wi = di * (cc) - dr * (ss);       \
            v1r = up ? wr : (v1r + p1r);                                  \
            v1i = up ? wi : (v1i + p1i);                                  \
        }
        XSTAGE(32, c32, s32)
        XSTAGE(16, c16, s16)
        XSTAGE(8,  c8,  s8)
        XSTAGE(4,  c4,  s4)
        #undef XSTAGE

        // ---- stage h=2: twiddle 1 (j=0) or -i (j=1); role = bit1, j = bit0
        {
            const bool up = (l & 2) != 0;
            const bool j1 = (l & 1) != 0;
            float p0r = __shfl_xor(v0r, 2), p0i = __shfl_xor(v0i, 2);
            float p1r = __shfl_xor(v1r, 2), p1i = __shfl_xor(v1i, 2);
            float dr = p0r - v0r, di = p0i - v0i;
            float wr = j1 ? di : dr, wi = j1 ? -dr : di;
            v0r = up ? wr : (v0r + p0r);
            v0i = up ? wi : (v0i + p0i);
            dr = p1r - v1r; di = p1i - v1i;
            wr = j1 ? di : dr; wi = j1 ? -dr : di;
            v1r = up ? wr : (v1r + p1r);
            v1i = up ? wi : (v1i + p1i);
        }

        // ---- stage h=1: twiddle 1; role = bit0
        {
            const bool up = (l & 1) != 0;
            float p0r = __shfl_xor(v0r, 1), p0i = __shfl_xor(v0i, 1);
            float p1r = __shfl_xor(v1r, 1), p1i = __shfl_xor(v1i, 1);
            v0r = up ? (p0r - v0r) : (v0r + p0r);
            v0i = up ? (p0i - v0i) : (v0i + p0i);
            v1r = up ? (p1r - v1r) : (v1r + p1r);
            v1i = up ? (p1i - v1i) : (v1i + p1i);
        }

        // ---- scatter to natural order: (l, slot r) holds Z[2*brev6(l)+r]
        reinterpret_cast<float2*>(zre)[pn] = make_float2(v0r, v1r);
        reinterpret_cast<float2*>(zim)[pn] = make_float2(v0i, v1i);
        // single wave per block: compiler-inserted lgkmcnt ordering suffices

        // ---- rfft untangle, 2 bins per lane (k=l and k=l+64), + bin 128
        float* __restrict__ o = out + (size_t)f * NBINS;
        {
            float zkr = zre[l],   zki = zim[l];
            float zmr = zre[km0], zmi = zim[km0];
            float er  = 0.5f * (zkr + zmr);
            float ei  = 0.5f * (zki - zmi);
            float orr = 0.5f * (zki + zmi);
            float oi  = -0.5f * (zkr - zmr);
            float Xr = er + cu0 * orr + su0 * oi;
            float Xi = ei + cu0 * oi - su0 * orr;
            float mag = sqrtf(Xr * Xr + Xi * Xi);
            o[l] = __log2f(mag + 1e-8f) * 6.931471805599453f;
        }
        {
            float zkr = zre[l + 64], zki = zim[l + 64];
            float zmr = zre[km1],    zmi = zim[km1];
            float er  = 0.5f * (zkr + zmr);
            float ei  = 0.5f * (zki - zmi);
            float orr = 0.5f * (zki + zmi);
            float oi  = -0.5f * (zkr - zmr);
            float Xr = er + cu1 * orr + su1 * oi;
            float Xi = ei + cu1 * oi - su1 * orr;
            float mag = sqrtf(Xr * Xr + Xi * Xi);
            o[l + 64] = __log2f(mag + 1e-8f) * 6.931471805599453f;
        }
        if (l == 0) {
            float Xr = zre[0] - zim[0];        // k=128: Re(Z0) - Im(Z0)
            o[128] = __log2f(fabsf(Xr) + 1e-8f) * 6.931471805599453f;
        }
    }
}

extern "C" void kernel_launch(void* const* d_in, const int* in_sizes, int n_in,
                              void* d_out, int out_size, void* d_ws, size_t ws_size,
                              hipStream_t stream) {
    const float* sig = (const float*)d_in[0];
    float* out = (float*)d_out;
    (void)in_sizes; (void)n_in; (void)out_size; (void)d_ws; (void)ws_size;
    stft_kernel<<<dim3(NBLOCKS), dim3(64), 0, stream>>>(sig, out);
}

// Round 9
// 371.968 us; speedup vs baseline: 1.2452x; 1.0028x over previous
//
#include <hip/hip_runtime.h>
#include <math.h>

#define WL     256
#define HOP    128
#define NW     239      // (30720 - 256)/128 + 1
#define NBINS  129
#define NSAMP  30720
#define NROWS  (64*23)  // 1472
#define NFRAMES (NROWS * NW)   // 351,808
#define NWAVES  8192
#define FPB     43             // ceil(NFRAMES / NWAVES)
#define WPB     4              // waves per block (lifts 16-wg/CU occupancy cap)
#define NBLOCKS (NWAVES / WPB) // 2048

// 256-thread blocks = 4 independent 64-lane waves. Each wave processes FPB
// consecutive frames with all frame-invariant twiddles/window coeffs hoisted.
// 128-pt register FFT via shfl_xor; per-wave private LDS chunk for the
// natural-order scatter (no __syncthreads needed anywhere).
__global__ __launch_bounds__(256) void stft_kernel(const float* __restrict__ sig,
                                                   float* __restrict__ out) {
    const int l  = threadIdx.x & 63;       // lane
    const int wv = threadIdx.x >> 6;       // wave id within block

    __shared__ __align__(8) float zre[WPB][128];
    __shared__ __align__(8) float zim[WPB][128];
    float* __restrict__ zr = zre[wv];
    float* __restrict__ zi = zim[wv];

    // ======== frame-invariant per-lane constants (computed ONCE) ========
    // Hann: np.hanning(256) w(n) = 0.5 - 0.5*cospi(2n/255)
    const float w0 = 0.5f - 0.5f * cospif((float)(4 * l)       * (1.0f / 255.0f));
    const float w1 = 0.5f - 0.5f * cospif((float)(4 * l + 2)   * (1.0f / 255.0f));
    const float w2 = 0.5f - 0.5f * cospif((float)(4 * l + 256) * (1.0f / 255.0f));
    const float w3 = 0.5f - 0.5f * cospif((float)(4 * l + 258) * (1.0f / 255.0f));
    float c64, s64;  sincospif((float)l * (1.0f / 64.0f), &s64, &c64);
    float c32, s32;  sincospif((float)(l & 31) * (1.0f / 32.0f), &s32, &c32);
    float c16, s16;  sincospif((float)(l & 15) * (1.0f / 16.0f), &s16, &c16);
    float c8,  s8;   sincospif((float)(l & 7)  * (1.0f / 8.0f),  &s8,  &c8);
    float c4,  s4;   sincospif((float)(l & 3)  * (1.0f / 4.0f),  &s4,  &c4);
    float cu0, su0;  sincospif((float)l        * (1.0f / 128.0f), &su0, &cu0);  // k = l
    float cu1, su1;  sincospif((float)(l + 64) * (1.0f / 128.0f), &su1, &cu1);  // k = l+64
    const int pn  = (int)(__brev((unsigned)l) >> 26);  // brev6(l), scatter target
    const int km0 = (128 - l) & 127;                   // mirror index for k=l
    const int km1 = 64 - l;                            // mirror for k=l+64

    const int g    = blockIdx.x * WPB + wv;            // global wave id
    const int f0   = g * FPB;
    const int fend = (f0 + FPB < NFRAMES) ? f0 + FPB : NFRAMES;

    for (int f = f0; f < fend; ++f) {
        const int row = f / NW;            // wave-uniform -> scalar magic-mul
        const int w   = f - row * NW;
        const float* __restrict__ src = sig + (size_t)row * NSAMP + (size_t)w * HOP;

        // ---- load 4 samples (2x float2, coalesced), window, pack complex
        float2 xa = *reinterpret_cast<const float2*>(src + 2 * l);
        float2 xb = *reinterpret_cast<const float2*>(src + 2 * l + 128);
        float v0r = xa.x * w0, v0i = xa.y * w1;   // element l
        float v1r = xb.x * w2, v1i = xb.y * w3;   // element l+64

        // ---- stage h=64 (lane-local), W_128^l
        {
            float tr = v0r - v1r, ti = v0i - v1i;
            v0r += v1r; v0i += v1i;
            v1r = tr * c64 + ti * s64;            // (tr+i*ti)*(c - i*s)
            v1i = ti * c64 - tr * s64;
        }

        // ---- stages h = 32,16,8,4 (cross-lane, hoisted twiddles)
        #define XSTAGE(m, cc, ss)                                         \
        {                                                                 \
            const bool up = (l & (m)) != 0;                               \
            float p0r = __shfl_xor(v0r, (m)), p0i = __shfl_xor(v0i, (m)); \
            float p1r = __shfl_xor(v1r, (m)), p1i = __shfl_xor(v1i, (m)); \
            float dr = p0r - v0r, di = p0i - v0i;                         \
            float wr = dr * (cc) + di * (ss), wi = di * (cc) - dr * (ss); \
            v0r = up ? wr : (v0r + p0r);                                  \
            v0i = up ? wi : (v0i + p0i);                                  \
            dr = p1r - v1r; di = p1i - v1i;                               \
            wr = dr * (cc) + di * (ss); wi = di * (cc) - dr * (ss);       \
            v1r = up ? wr : (v1r + p1r);                                  \
            v1i = up ? wi : (v1i + p1i);                                  \
        }
        XSTAGE(32, c32, s32)
        XSTAGE(16, c16, s16)
        XSTAGE(8,  c8,  s8)
        XSTAGE(4,  c4,  s4)
        #undef XSTAGE

        // ---- stage h=2: twiddle 1 (j=0) or -i (j=1); role = bit1, j = bit0
        {
            const bool up = (l & 2) != 0;
            const bool j1 = (l & 1) != 0;
            float p0r = __shfl_xor(v0r, 2), p0i = __shfl_xor(v0i, 2);
            float p1r = __shfl_xor(v1r, 2), p1i = __shfl_xor(v1i, 2);
            float dr = p0r - v0r, di = p0i - v0i;
            float wr = j1 ? di : dr, wi = j1 ? -dr : di;
            v0r = up ? wr : (v0r + p0r);
            v0i = up ? wi : (v0i + p0i);
            dr = p1r - v1r; di = p1i - v1i;
            wr = j1 ? di : dr; wi = j1 ? -dr : di;
            v1r = up ? wr : (v1r + p1r);
            v1i = up ? wi : (v1i + p1i);
        }

        // ---- stage h=1: twiddle 1; role = bit0
        {
            const bool up = (l & 1) != 0;
            float p0r = __shfl_xor(v0r, 1), p0i = __shfl_xor(v0i, 1);
            float p1r = __shfl_xor(v1r, 1), p1i = __shfl_xor(v1i, 1);
            v0r = up ? (p0r - v0r) : (v0r + p0r);
            v0i = up ? (p0i - v0i) : (v0i + p0i);
            v1r = up ? (p1r - v1r) : (v1r + p1r);
            v1i = up ? (p1i - v1i) : (v1i + p1i);
        }

        // ---- scatter to natural order: (l, slot r) holds Z[2*brev6(l)+r]
        reinterpret_cast<float2*>(zr)[pn] = make_float2(v0r, v1r);
        reinterpret_cast<float2*>(zi)[pn] = make_float2(v0i, v1i);
        // per-wave private LDS chunk; wave-synchronous -> no barrier needed

        // ---- rfft untangle, 2 bins per lane (k=l and k=l+64), + bin 128
        float* __restrict__ o = out + (size_t)f * NBINS;
        {
            float zkr = zr[l],   zki = zi[l];
            float zmr = zr[km0], zmi = zi[km0];
            float er  = 0.5f * (zkr + zmr);
            float ei  = 0.5f * (zki - zmi);
            float orr = 0.5f * (zki + zmi);
            float oi  = -0.5f * (zkr - zmr);
            float Xr = er + cu0 * orr + su0 * oi;
            float Xi = ei + cu0 * oi - su0 * orr;
            float mag = sqrtf(Xr * Xr + Xi * Xi);
            o[l] = __log2f(mag + 1e-8f) * 6.931471805599453f;
        }
        {
            float zkr = zr[l + 64], zki = zi[l + 64];
            float zmr = zr[km1],    zmi = zi[km1];
            float er  = 0.5f * (zkr + zmr);
            float ei  = 0.5f * (zki - zmi);
            float orr = 0.5f * (zki + zmi);
            float oi  = -0.5f * (zkr - zmr);
            float Xr = er + cu1 * orr + su1 * oi;
            float Xi = ei + cu1 * oi - su1 * orr;
            float mag = sqrtf(Xr * Xr + Xi * Xi);
            o[l + 64] = __log2f(mag + 1e-8f) * 6.931471805599453f;
        }
        if (l == 0) {
            float Xr = zr[0] - zi[0];          // k=128: Re(Z0) - Im(Z0)
            o[128] = __log2f(fabsf(Xr) + 1e-8f) * 6.931471805599453f;
        }
    }
}

extern "C" void kernel_launch(void* const* d_in, const int* in_sizes, int n_in,
                              void* d_out, int out_size, void* d_ws, size_t ws_size,
                              hipStream_t stream) {
    const float* sig = (const float*)d_in[0];
    float* out = (float*)d_out;
    (void)in_sizes; (void)n_in; (void)out_size; (void)d_ws; (void)ws_size;
    stft_kernel<<<dim3(NBLOCKS), dim3(256), 0, stream>>>(sig, out);
}